// Round 2
// baseline (693.041 us; speedup 1.0000x reference)
//
#include <hip/hip_runtime.h>
#include <math.h>

#define N_NODES 20000
#define E_EDGES 320000
#define NHEADS 4
#define RMIN 2.2e-10f
#define THETA_MAX 1000.0f
#define SLOPE 0.2f

__device__ __forceinline__ float softplus_f(float x) {
    // log(1+exp(x)), stable; matches jax.nn.softplus
    return fmaxf(x, 0.0f) + log1pf(expf(-fabsf(x)));
}

// ---------------- CSR build ----------------
__global__ __launch_bounds__(256) void count_kernel(const int* __restrict__ dst,
                                                    int* __restrict__ deg) {
    int e = blockIdx.x * 256 + threadIdx.x;
    if (e < E_EDGES) atomicAdd(&deg[dst[e]], 1);
}

__global__ __launch_bounds__(256) void scan_kernel(const int* __restrict__ deg,
                                                   int* __restrict__ rowptr,
                                                   int* __restrict__ cursor) {
    __shared__ int part[256];
    int t = threadIdx.x;
    const int CH = (N_NODES + 255) / 256;  // 79
    int base = t * CH;
    int sum = 0;
    for (int i = 0; i < CH; ++i) {
        int idx = base + i;
        if (idx < N_NODES) sum += deg[idx];
    }
    part[t] = sum;
    __syncthreads();
    // Hillis-Steele inclusive scan
    for (int off = 1; off < 256; off <<= 1) {
        int v = (t >= off) ? part[t - off] : 0;
        __syncthreads();
        part[t] += v;
        __syncthreads();
    }
    int run = (t == 0) ? 0 : part[t - 1];
    for (int i = 0; i < CH; ++i) {
        int idx = base + i;
        if (idx < N_NODES) {
            rowptr[idx] = run;
            cursor[idx] = run;
            run += deg[idx];
        }
    }
    if (t == 255) rowptr[N_NODES] = run;
}

__global__ __launch_bounds__(256) void scatter_kernel(const int* __restrict__ src,
                                                      const int* __restrict__ dst,
                                                      int* __restrict__ cursor,
                                                      int* __restrict__ csr) {
    int e = blockIdx.x * 256 + threadIdx.x;
    if (e < E_EDGES) {
        int p = atomicAdd(&cursor[dst[e]], 1);
        csr[p] = src[e];
    }
}

// ---------------- GEMM: out[M,NO] = A[M,K] * W[NO,K]^T, 64x64 tile ----------------
// MODE: 0 raw, 1 softplus(v+b), 2 clip(softplus(v+b),0.1,1000), 3 max(softplus(v+b),RMIN)
// TRANS: write out[col*M + row] (i.e. [NO, M] layout)
template <int MODE, bool TRANS>
__global__ __launch_bounds__(256) void gemm_kernel(const float* __restrict__ A,
                                                   const float* __restrict__ W,
                                                   const float* __restrict__ bias,
                                                   float* __restrict__ out,
                                                   int M, int K, int NO) {
    __shared__ float As[16][68];
    __shared__ float Bs[16][68];
    int tid = threadIdx.x;
    int tx = tid & 15, ty = tid >> 4;
    int bm = blockIdx.x * 64;
    int bn = blockIdx.y * 64;
    float acc[4][4] = {};
    for (int k0 = 0; k0 < K; k0 += 16) {
        {
            int m = tid >> 2;
            int kk0 = (tid & 3) * 4;
            int row = bm + m;
            float4 v = make_float4(0.f, 0.f, 0.f, 0.f);
            if (row < M) v = *(const float4*)(A + (size_t)row * K + k0 + kk0);
            As[kk0 + 0][m] = v.x; As[kk0 + 1][m] = v.y;
            As[kk0 + 2][m] = v.z; As[kk0 + 3][m] = v.w;
        }
        {
            int o = tid >> 2;
            int kk0 = (tid & 3) * 4;
            float4 v = *(const float4*)(W + (size_t)(bn + o) * K + k0 + kk0);
            Bs[kk0 + 0][o] = v.x; Bs[kk0 + 1][o] = v.y;
            Bs[kk0 + 2][o] = v.z; Bs[kk0 + 3][o] = v.w;
        }
        __syncthreads();
#pragma unroll
        for (int kk = 0; kk < 16; ++kk) {
            float a[4], b[4];
            *(float4*)a = *(const float4*)(&As[kk][ty * 4]);
            *(float4*)b = *(const float4*)(&Bs[kk][tx * 4]);
#pragma unroll
            for (int i = 0; i < 4; ++i)
#pragma unroll
                for (int j = 0; j < 4; ++j) acc[i][j] += a[i] * b[j];
        }
        __syncthreads();
    }
    int r0 = bm + ty * 4;
    int c0 = bn + tx * 4;
    float bv[4] = {0.f, 0.f, 0.f, 0.f};
    if (MODE != 0) *(float4*)bv = *(const float4*)(bias + c0);
    float vals[4][4];
#pragma unroll
    for (int i = 0; i < 4; ++i)
#pragma unroll
        for (int j = 0; j < 4; ++j) {
            float v = acc[i][j];
            if (MODE == 1) v = softplus_f(v + bv[j]);
            else if (MODE == 2) { v = softplus_f(v + bv[j]); v = fminf(fmaxf(v, 0.1f), 1000.0f); }
            else if (MODE == 3) { v = fmaxf(softplus_f(v + bv[j]), RMIN); }
            vals[i][j] = v;
        }
    if (!TRANS) {
#pragma unroll
        for (int i = 0; i < 4; ++i) {
            int row = r0 + i;
            if (row < M) *(float4*)(out + (size_t)row * NO + c0) = *(float4*)vals[i];
        }
    } else {
        if (r0 + 3 < M) {
#pragma unroll
            for (int j = 0; j < 4; ++j) {
                float col[4] = {vals[0][j], vals[1][j], vals[2][j], vals[3][j]};
                *(float4*)(out + (size_t)(c0 + j) * M + r0) = *(float4*)col;
            }
        } else {
#pragma unroll
            for (int i = 0; i < 4; ++i) {
                int row = r0 + i;
                if (row < M)
#pragma unroll
                    for (int j = 0; j < 4; ++j) out[(size_t)(c0 + j) * M + row] = vals[i][j];
            }
        }
    }
}

// ---------------- per-node attention logits s,d ----------------
template <int F, int CPER>
__global__ __launch_bounds__(256) void sd_kernel(const float* __restrict__ xw,
                                                 const float* __restrict__ asrc,
                                                 const float* __restrict__ adst,
                                                 float* __restrict__ s,
                                                 float* __restrict__ d) {
    int wave = threadIdx.x >> 6;
    int lane = threadIdx.x & 63;
    int n = blockIdx.x * 4 + wave;
    if (n >= N_NODES) return;
    float ss[NHEADS] = {0, 0, 0, 0}, dd[NHEADS] = {0, 0, 0, 0};
#pragma unroll
    for (int j = 0; j < F / 64; ++j) {
        int c = j * 64 + lane;
        int h = c / CPER;
        int cc = c % CPER;
        float v = xw[(size_t)n * F + c];
        ss[h] += v * asrc[h * CPER + cc];
        dd[h] += v * adst[h * CPER + cc];
    }
#pragma unroll
    for (int off = 32; off > 0; off >>= 1) {
#pragma unroll
        for (int h = 0; h < NHEADS; ++h) {
            ss[h] += __shfl_xor(ss[h], off, 64);
            dd[h] += __shfl_xor(dd[h], off, 64);
        }
    }
    if (lane == 0) {
#pragma unroll
        for (int h = 0; h < NHEADS; ++h) {
            s[n * NHEADS + h] = ss[h];
            d[n * NHEADS + h] = dd[h];
        }
    }
}

// ---------------- GAT aggregation: one wave per node ----------------
template <int F, int CPER>
__global__ __launch_bounds__(256) void agg_kernel(const float* __restrict__ xw,
                                                  const float* __restrict__ s,
                                                  const float* __restrict__ d,
                                                  const int* __restrict__ rowptr,
                                                  const int* __restrict__ csr,
                                                  const float* __restrict__ bias,
                                                  float* __restrict__ out) {
    int wave = threadIdx.x >> 6;
    int lane = threadIdx.x & 63;
    int n = blockIdx.x * 4 + wave;
    if (n >= N_NODES) return;
    constexpr int J = F / 64;
    float dh[NHEADS], shh[NHEADS];
#pragma unroll
    for (int h = 0; h < NHEADS; ++h) {
        dh[h] = d[n * NHEADS + h];
        shh[h] = s[n * NHEADS + h];
    }
    float den[NHEADS], w[NHEADS], acc[J];
#pragma unroll
    for (int h = 0; h < NHEADS; ++h) {
        float e = shh[h] + dh[h];
        e = e > 0.f ? e : SLOPE * e;
        w[h] = expf(e);
        den[h] = w[h];
    }
#pragma unroll
    for (int j = 0; j < J; ++j) {
        int c = j * 64 + lane;
        acc[j] = w[c / CPER] * xw[(size_t)n * F + c];
    }
    int beg = rowptr[n], end = rowptr[n + 1];
    for (int idx = beg; idx < end; ++idx) {
        int srcn = csr[idx];
#pragma unroll
        for (int h = 0; h < NHEADS; ++h) {
            float e = s[srcn * NHEADS + h] + dh[h];
            e = e > 0.f ? e : SLOPE * e;
            w[h] = expf(e);
            den[h] += w[h];
        }
#pragma unroll
        for (int j = 0; j < J; ++j) {
            int c = j * 64 + lane;
            acc[j] += w[c / CPER] * xw[(size_t)srcn * F + c];
        }
    }
#pragma unroll
    for (int j = 0; j < J; ++j) {
        int c = j * 64 + lane;
        out[(size_t)n * F + c] = acc[j] / (den[c / CPER] + 1e-16f) + bias[c];
    }
}

// ---------------- Weibull reparameterization ----------------
__global__ __launch_bounds__(256) void theta_kernel(const float* __restrict__ eps,
                                                    const float* __restrict__ kptr,
                                                    float* __restrict__ lptr,
                                                    float* __restrict__ theta, int ZN) {
    int i = blockIdx.x * 256 + threadIdx.x;
    if (i >= ZN) return;
    float k = kptr[i];
    float invk = 1.0f / k;
    float lg = expf(lgammaf(1.0f + invk));
    float l = lptr[i] / lg;
    lptr[i] = l;
    float acc = 0.0f;
#pragma unroll
    for (int ss = 0; ss < 10; ++ss) {
        float u = eps[(size_t)ss * ZN + i];
        float v = -logf(fmaxf(1.0f - u, RMIN));
        // v^invk = exp2(log2(v)*invk); v==0 -> log2=-inf -> 0, matches power semantics
        acc += exp2f(log2f(v) * invk);
    }
    float th = l * acc * 0.1f;
    th = fminf(fmaxf(th, RMIN), THETA_MAX);
    theta[i] = th;
}

extern "C" void kernel_launch(void* const* d_in, const int* in_sizes, int n_in,
                              void* d_out, int out_size, void* d_ws, size_t ws_size,
                              hipStream_t stream) {
    const float* x     = (const float*)d_in[0];
    const int*   eidx  = (const int*)d_in[1];
    const float* gatW0 = (const float*)d_in[2];
    const float* asrc0 = (const float*)d_in[3];
    const float* adst0 = (const float*)d_in[4];
    const float* gatb0 = (const float*)d_in[5];
    const float* fcW0  = (const float*)d_in[6];
    const float* fcb0  = (const float*)d_in[7];
    const float* shW0  = (const float*)d_in[8];
    const float* shb0  = (const float*)d_in[9];
    const float* scW0  = (const float*)d_in[10];
    const float* scb0  = (const float*)d_in[11];
    const float* gatW1 = (const float*)d_in[12];
    const float* asrc1 = (const float*)d_in[13];
    const float* adst1 = (const float*)d_in[14];
    const float* gatb1 = (const float*)d_in[15];
    const float* fcW1  = (const float*)d_in[16];
    const float* fcb1  = (const float*)d_in[17];
    const float* shW1  = (const float*)d_in[18];
    const float* shb1  = (const float*)d_in[19];
    const float* scW1  = (const float*)d_in[20];
    const float* scb1  = (const float*)d_in[21];
    const float* eps0  = (const float*)d_in[22];
    const float* eps1  = (const float*)d_in[23];

    const int* e_src = eidx;
    const int* e_dst = eidx + E_EDGES;

    // workspace carve-up
    size_t off = 0;
    auto carve = [&](size_t elems) {
        void* p = (char*)d_ws + off;
        off += ((elems * 4 + 255) / 256) * 256;
        return p;
    };
    float* xw0 = (float*)carve(20000u * 256);
    float* h0  = (float*)carve(20000u * 256);
    float* z0  = (float*)carve(20000u * 128);
    float* xw1 = (float*)carve(20000u * 128);
    float* h1  = (float*)carve(20000u * 128);
    float* z1  = (float*)carve(20000u * 64);
    float* s0  = (float*)carve(20000u * 4);
    float* d0  = (float*)carve(20000u * 4);
    float* s1  = (float*)carve(20000u * 4);
    float* d1  = (float*)carve(20000u * 4);
    int* deg    = (int*)carve(20000);
    int* rowptr = (int*)carve(20001);
    int* cursor = (int*)carve(20000);
    int* csr    = (int*)carve(E_EDGES);

    float* out    = (float*)d_out;
    float* theta0 = out;
    float* theta1 = out + 2560000;
    float* k0     = out + 3840000;
    float* k1     = out + 6400000;
    float* l0     = out + 7680000;
    float* l1     = out + 10240000;

    const int M = N_NODES;
    dim3 blk(256);

    // CSR build
    (void)hipMemsetAsync(deg, 0, N_NODES * sizeof(int), stream);
    count_kernel<<<(E_EDGES + 255) / 256, blk, 0, stream>>>(e_dst, deg);
    scan_kernel<<<1, blk, 0, stream>>>(deg, rowptr, cursor);
    scatter_kernel<<<(E_EDGES + 255) / 256, blk, 0, stream>>>(e_src, e_dst, cursor, csr);

    // layer 0
    gemm_kernel<0, false><<<dim3(313, 4), blk, 0, stream>>>(x, gatW0, nullptr, xw0, M, 256, 256);
    sd_kernel<256, 64><<<5000, blk, 0, stream>>>(xw0, asrc0, adst0, s0, d0);
    agg_kernel<256, 64><<<5000, blk, 0, stream>>>(xw0, s0, d0, rowptr, csr, gatb0, h0);
    gemm_kernel<1, false><<<dim3(313, 2), blk, 0, stream>>>(h0, fcW0, fcb0, z0, M, 256, 128);

    // layer 1
    gemm_kernel<0, false><<<dim3(313, 2), blk, 0, stream>>>(h0, gatW1, nullptr, xw1, M, 256, 128);
    sd_kernel<128, 32><<<5000, blk, 0, stream>>>(xw1, asrc1, adst1, s1, d1);
    agg_kernel<128, 32><<<5000, blk, 0, stream>>>(xw1, s1, d1, rowptr, csr, gatb1, h1);
    gemm_kernel<1, false><<<dim3(313, 1), blk, 0, stream>>>(h1, fcW1, fcb1, z1, M, 128, 64);

    // heads: k and raw l (transposed [z, N] into d_out)
    gemm_kernel<2, true><<<dim3(313, 2), blk, 0, stream>>>(z0, shW0, shb0, k0, M, 128, 128);
    gemm_kernel<3, true><<<dim3(313, 2), blk, 0, stream>>>(z0, scW0, scb0, l0, M, 128, 128);
    gemm_kernel<2, true><<<dim3(313, 1), blk, 0, stream>>>(z1, shW1, shb1, k1, M, 64, 64);
    gemm_kernel<3, true><<<dim3(313, 1), blk, 0, stream>>>(z1, scW1, scb1, l1, M, 64, 64);

    // reparameterize (finalizes l in-place, writes theta)
    theta_kernel<<<(2560000 + 255) / 256, blk, 0, stream>>>(eps0, k0, l0, theta0, 2560000);
    theta_kernel<<<(1280000 + 255) / 256, blk, 0, stream>>>(eps1, k1, l1, theta1, 1280000);
}